// Round 2
// baseline (31.765 us; speedup 1.0000x reference)
//
#include <hip/hip_runtime.h>
#include <hip/hip_bf16.h>

// h = dot(feat, W1) + b1 decomposes per edge as:
//   h = ph[src] + pg[tgt] + pu[graph] + dot(edge_attr_e, W1[128:136])
// where ph[i] = dot(x_h[i], W1[0:64]), pg[j] = dot(x_g[j], W1[64:128]),
//       pu[g] = dot(u[g], W1[136:152]) + b1.
// out = leaky(h, 0.1) * W2 + b2

// One 16-lane group per row; rows [0,nh) -> ph, [nh,nh+ng) -> pg, rest -> pu.
__global__ void precompute_partials(const float* __restrict__ xh,
                                    const float* __restrict__ xg,
                                    const float* __restrict__ u,
                                    const float* __restrict__ W1,
                                    const float* __restrict__ b1,
                                    float* __restrict__ ph,
                                    float* __restrict__ pg,
                                    float* __restrict__ pu,
                                    int nh, int ng, int ngr) {
    int gid = blockIdx.x * blockDim.x + threadIdx.x;
    int row = gid >> 4;          // 16-lane group id
    int q   = gid & 15;
    int total = nh + ng + ngr;
    if (row >= total) return;

    if (row < nh + ng) {
        const float* src = (row < nh) ? xh + (size_t)row * 64
                                      : xg + (size_t)(row - nh) * 64;
        const float* w   = (row < nh) ? W1 : W1 + 64;
        float4 v  = reinterpret_cast<const float4*>(src)[q];
        float4 wv = reinterpret_cast<const float4*>(w)[q];
        float s = v.x * wv.x + v.y * wv.y + v.z * wv.z + v.w * wv.w;
        s += __shfl_xor(s, 1);
        s += __shfl_xor(s, 2);
        s += __shfl_xor(s, 4);
        s += __shfl_xor(s, 8);
        if (q == 0) {
            if (row < nh) ph[row] = s;
            else          pg[row - nh] = s;
        }
    } else {
        int g = row - nh - ng;
        float s = 0.0f;
        if (q < 4) {
            float4 v  = reinterpret_cast<const float4*>(u + (size_t)g * 16)[q];
            float4 wv = reinterpret_cast<const float4*>(W1 + 136)[q];
            s = v.x * wv.x + v.y * wv.y + v.z * wv.z + v.w * wv.w;
        }
        s += __shfl_xor(s, 1);
        s += __shfl_xor(s, 2);
        if (q == 0) pu[g] = s + b1[0];
    }
}

// 4 edges per thread: int4 index loads, float4 edge_attr loads, float4 store.
__global__ void edge_kernel4(const int* __restrict__ edge_index,
                             const int* __restrict__ batch_e,
                             const float* __restrict__ edge_attr,
                             const float* __restrict__ W1,
                             const float* __restrict__ W2,
                             const float* __restrict__ b2,
                             const float* __restrict__ ph,
                             const float* __restrict__ pg,
                             const float* __restrict__ pu,
                             float* __restrict__ out,
                             int E) {
    int t = blockIdx.x * blockDim.x + threadIdx.x;
    int base = t * 4;
    if (base >= E) return;

    const float* wx = W1 + 128;
    float w0 = wx[0], w1 = wx[1], w2 = wx[2], w3 = wx[3];
    float w4 = wx[4], w5 = wx[5], w6 = wx[6], w7 = wx[7];
    float w2s = W2[0], b2s = b2[0];

    if (base + 3 < E) {
        int4 sv = *reinterpret_cast<const int4*>(edge_index + base);
        int4 tv = *reinterpret_cast<const int4*>(edge_index + E + base);
        int4 gv = *reinterpret_cast<const int4*>(batch_e + base);

        const float4* eap = reinterpret_cast<const float4*>(edge_attr + (size_t)base * 8);
        float4 ea[8];
#pragma unroll
        for (int j = 0; j < 8; ++j) ea[j] = eap[j];

        // issue all 12 random/table gathers up front (independent -> MLP)
        float p0 = ph[sv.x], p1 = ph[sv.y], p2 = ph[sv.z], p3 = ph[sv.w];
        float q0 = pg[tv.x], q1 = pg[tv.y], q2 = pg[tv.z], q3 = pg[tv.w];
        float r0 = pu[gv.x], r1 = pu[gv.y], r2 = pu[gv.z], r3 = pu[gv.w];

        float hv[4];
        float pp[4] = {p0, p1, p2, p3};
        float qq[4] = {q0, q1, q2, q3};
        float rr[4] = {r0, r1, r2, r3};
#pragma unroll
        for (int i = 0; i < 4; ++i) {
            float4 a0 = ea[2 * i], a1 = ea[2 * i + 1];
            float h = pp[i] + qq[i] + rr[i]
                    + a0.x * w0 + a0.y * w1 + a0.z * w2 + a0.w * w3
                    + a1.x * w4 + a1.y * w5 + a1.z * w6 + a1.w * w7;
            h = (h >= 0.0f) ? h : 0.1f * h;
            hv[i] = h * w2s + b2s;
        }
        *reinterpret_cast<float4*>(out + base) = make_float4(hv[0], hv[1], hv[2], hv[3]);
    } else {
        for (int e = base; e < E; ++e) {
            int s = edge_index[e];
            int tg = edge_index[E + e];
            int g = batch_e[e];
            const float* a = edge_attr + (size_t)e * 8;
            float h = ph[s] + pg[tg] + pu[g]
                    + a[0] * w0 + a[1] * w1 + a[2] * w2 + a[3] * w3
                    + a[4] * w4 + a[5] * w5 + a[6] * w6 + a[7] * w7;
            h = (h >= 0.0f) ? h : 0.1f * h;
            out[e] = h * w2s + b2s;
        }
    }
}

// Fallback if workspace too small: direct gather per edge.
__global__ void edge_fallback(const int* __restrict__ edge_index,
                              const int* __restrict__ batch_e,
                              const float* __restrict__ xh,
                              const float* __restrict__ xg,
                              const float* __restrict__ edge_attr,
                              const float* __restrict__ u,
                              const float* __restrict__ W1,
                              const float* __restrict__ b1,
                              const float* __restrict__ W2,
                              const float* __restrict__ b2,
                              float* __restrict__ out,
                              int E) {
    int e = blockIdx.x * blockDim.x + threadIdx.x;
    if (e >= E) return;
    int s = edge_index[e];
    int t = edge_index[E + e];
    int g = batch_e[e];
    float h = b1[0];
    const float* hs = xh + (size_t)s * 64;
    const float* gt = xg + (size_t)t * 64;
#pragma unroll 8
    for (int j = 0; j < 64; ++j) h += hs[j] * W1[j];
#pragma unroll 8
    for (int j = 0; j < 64; ++j) h += gt[j] * W1[64 + j];
    const float* ea = edge_attr + (size_t)e * 8;
#pragma unroll
    for (int j = 0; j < 8; ++j) h += ea[j] * W1[128 + j];
    const float* ug = u + (size_t)g * 16;
#pragma unroll
    for (int j = 0; j < 16; ++j) h += ug[j] * W1[136 + j];
    h = (h >= 0.0f) ? h : 0.1f * h;
    out[e] = h * W2[0] + b2[0];
}

extern "C" void kernel_launch(void* const* d_in, const int* in_sizes, int n_in,
                              void* d_out, int out_size, void* d_ws, size_t ws_size,
                              hipStream_t stream) {
    const float* x_h       = (const float*)d_in[0];
    const float* x_g       = (const float*)d_in[1];
    const float* edge_attr = (const float*)d_in[2];
    const float* u         = (const float*)d_in[3];
    const int*   edge_idx  = (const int*)d_in[4];
    const int*   batch_e   = (const int*)d_in[5];
    const float* W1        = (const float*)d_in[6];
    const float* b1        = (const float*)d_in[7];
    const float* W2        = (const float*)d_in[8];
    const float* b2        = (const float*)d_in[9];
    float* out = (float*)d_out;

    const int E   = in_sizes[5];        // N_EDGES
    const int nh  = in_sizes[0] / 64;   // N_H_NODES
    const int ng  = in_sizes[1] / 64;   // N_G_NODES
    const int ngr = in_sizes[3] / 16;   // N_GRAPHS

    size_t need = (size_t)(nh + ng + ngr) * sizeof(float);
    if (ws_size >= need) {
        float* ph = (float*)d_ws;
        float* pg = ph + nh;
        float* pu = pg + ng;

        int totalRows = nh + ng + ngr;
        int rowsPerBlock = 16;                 // 256 threads / 16 lanes per row
        int nb = (totalRows + rowsPerBlock - 1) / rowsPerBlock;
        precompute_partials<<<nb, 256, 0, stream>>>(x_h, x_g, u, W1, b1,
                                                    ph, pg, pu, nh, ng, ngr);

        int threads = (E + 3) / 4;
        int eb = (threads + 255) / 256;
        edge_kernel4<<<eb, 256, 0, stream>>>(edge_idx, batch_e, edge_attr,
                                             W1, W2, b2, ph, pg, pu, out, E);
    } else {
        int eb = (E + 255) / 256;
        edge_fallback<<<eb, 256, 0, stream>>>(edge_idx, batch_e, x_h, x_g, edge_attr, u,
                                              W1, b1, W2, b2, out, E);
    }
}